// Round 10
// baseline (490.805 us; speedup 1.0000x reference)
//
#include <hip/hip_runtime.h>

#define NEG_SLOPE 0.2f

typedef float f32x4 __attribute__((ext_vector_type(4)));
typedef short bf16x8 __attribute__((ext_vector_type(8)));
typedef float nf4 __attribute__((ext_vector_type(4)));

__device__ __forceinline__ float lrelu(float x) { return x > 0.0f ? x : NEG_SLOPE * x; }

// pack two floats as bf16 (RNE) into one uint: low16 = a, high16 = b
__device__ __forceinline__ unsigned pack_bf16(float a, float b) {
  unsigned ua = __float_as_uint(a), ub = __float_as_uint(b);
  ua += 0x7fffu + ((ua >> 16) & 1u);
  ub += 0x7fffu + ((ub >> 16) & 1u);
  return (ua >> 16) | (ub & 0xffff0000u);
}
__device__ __forceinline__ unsigned short bf16of(float a) {
  unsigned ua = __float_as_uint(a);
  ua += 0x7fffu + ((ua >> 16) & 1u);
  return (unsigned short)(ua >> 16);
}
__device__ __forceinline__ float bf16lo(unsigned z) { return __uint_as_float(z << 16); }
__device__ __forceinline__ float bf16hi(unsigned z) { return __uint_as_float(z & 0xffff0000u); }

// ---------------------------------------------------------------------------
// K0: fold all small weights + zero deg (memset folded in).
// Wzb = bf16(W @ proj_W) in MFMA-B-fragment layout.
// ---------------------------------------------------------------------------
__global__ void k0_setup(const float* __restrict__ W, const float* __restrict__ proj_W,
                         const float* __restrict__ att_src, const float* __restrict__ att_dst,
                         const float* __restrict__ lin_edge_W, const float* __restrict__ att_edge,
                         const float* __restrict__ bias, const float* __restrict__ proj_b,
                         unsigned short* __restrict__ Wzb, float* __restrict__ Ws,
                         float* __restrict__ Wd, float* __restrict__ M, float* __restrict__ cproj,
                         int n, int* __restrict__ deg) {
  int t = blockIdx.x * blockDim.x + threadIdx.x;
  if (t < n) deg[t] = 0;
  if (t < 16384) {
    int d = t >> 7, o = t & 127;
    int h = o >> 5, jj = o & 31;
    float s = 0.f;
    #pragma unroll
    for (int c = 0; c < 32; ++c)
      s += W[d * 128 + h * 32 + c] * proj_W[(h * 32 + c) * 32 + jj];
    Wzb[((d >> 3) * 128 + o) * 8 + (d & 7)] = bf16of(s);
  } else if (t < 16384 + 512) {
    int idx = t - 16384; int d = idx >> 2, h = idx & 3;
    float s = 0.f;
    #pragma unroll
    for (int c = 0; c < 32; ++c) s += W[d * 128 + h * 32 + c] * att_src[h * 32 + c];
    Ws[d * 4 + h] = s;
  } else if (t < 16384 + 1024) {
    int idx = t - 16384 - 512; int d = idx >> 2, h = idx & 3;
    float s = 0.f;
    #pragma unroll
    for (int c = 0; c < 32; ++c) s += W[d * 128 + h * 32 + c] * att_dst[h * 32 + c];
    Wd[d * 4 + h] = s;
  } else if (t < 16384 + 1024 + 128) {
    int idx = t - 16384 - 1024; int d = idx >> 2, h = idx & 3;
    float s = 0.f;
    #pragma unroll
    for (int c = 0; c < 32; ++c) s += lin_edge_W[d * 128 + h * 32 + c] * att_edge[h * 32 + c];
    M[d * 4 + h] = s;
  } else if (t < 16384 + 1024 + 128 + 32) {
    int jj = t - 16384 - 1024 - 128;
    float s = proj_b[jj];
    #pragma unroll
    for (int k = 0; k < 128; ++k) s += bias[k] * proj_W[k * 32 + jj];
    cproj[jj] = s;
  }
}

// ---------------------------------------------------------------------------
// K3: fused. Zp = bf16pack(x @ Wz) via MFMA 16x16x32 bf16, AND a_src/a_dst
// from the SAME f32 x registers. x loads are non-temporal (single-use).
// ---------------------------------------------------------------------------
__global__ __launch_bounds__(256) void k3_gemm(
    const float* __restrict__ x, const unsigned short* __restrict__ Wzb,
    const float* __restrict__ Ws, const float* __restrict__ Wd,
    int n, unsigned* __restrict__ Zp, float* __restrict__ a_src, float* __restrict__ a_dst) {
  __shared__ __align__(16) unsigned short WzL[16384];
  __shared__ float4 WsL[128];
  __shared__ float4 WdL[128];
  int tid = threadIdx.x;
  #pragma unroll
  for (int i = 0; i < 8; ++i)
    *(uint4*)&WzL[(i * 256 + tid) * 8] = *(const uint4*)&Wzb[(i * 256 + tid) * 8];
  if (tid < 128) {
    WsL[tid] = ((const float4*)Ws)[tid];
    WdL[tid] = ((const float4*)Wd)[tid];
  }
  __syncthreads();
  int lane = tid & 63, wid = tid >> 6;
  int rgrp = lane >> 4, rl = lane & 15;
  int r0 = blockIdx.x * 64 + wid * 16;
  if (r0 >= n) return;
  int row = r0 + rl;
  bool rowok = row < n;
  int rowc = rowok ? row : n - 1;
  const float* xr = x + (size_t)rowc * 128 + rgrp * 8;
  bf16x8 a[4];
  float ps[4] = {0.f, 0.f, 0.f, 0.f}, pd[4] = {0.f, 0.f, 0.f, 0.f};
  #pragma unroll
  for (int q = 0; q < 4; ++q) {
    nf4 v0 = __builtin_nontemporal_load((const nf4*)(xr + q * 32));
    nf4 v1 = __builtin_nontemporal_load((const nf4*)(xr + q * 32 + 4));
    int d0 = q * 32 + rgrp * 8;
    float vv[8] = {v0.x, v0.y, v0.z, v0.w, v1.x, v1.y, v1.z, v1.w};
    #pragma unroll
    for (int i = 0; i < 8; ++i) {
      float4 ws = WsL[d0 + i], wd = WdL[d0 + i];
      ps[0] += vv[i] * ws.x; ps[1] += vv[i] * ws.y;
      ps[2] += vv[i] * ws.z; ps[3] += vv[i] * ws.w;
      pd[0] += vv[i] * wd.x; pd[1] += vv[i] * wd.y;
      pd[2] += vv[i] * wd.z; pd[3] += vv[i] * wd.w;
    }
    union { unsigned u[4]; bf16x8 v; } fa;
    fa.u[0] = pack_bf16(v0.x, v0.y); fa.u[1] = pack_bf16(v0.z, v0.w);
    fa.u[2] = pack_bf16(v1.x, v1.y); fa.u[3] = pack_bf16(v1.z, v1.w);
    a[q] = fa.v;
  }
  #pragma unroll
  for (int m = 16; m < 64; m <<= 1) {
    #pragma unroll
    for (int h = 0; h < 4; ++h) {
      ps[h] += __shfl_xor(ps[h], m);
      pd[h] += __shfl_xor(pd[h], m);
    }
  }
  if (rgrp == 0 && rowok) {
    *(float4*)&a_src[(size_t)row * 4] = make_float4(ps[0], ps[1], ps[2], ps[3]);
    *(float4*)&a_dst[(size_t)row * 4] = make_float4(pd[0], pd[1], pd[2], pd[3]);
  }
  f32x4 acc[8];
  #pragma unroll
  for (int t = 0; t < 8; ++t) acc[t] = (f32x4){0.f, 0.f, 0.f, 0.f};
  #pragma unroll
  for (int q = 0; q < 4; ++q) {
    #pragma unroll
    for (int t = 0; t < 8; ++t) {
      bf16x8 b = *(const bf16x8*)&WzL[((q * 4 + rgrp) * 128 + t * 16 + rl) * 8];
      acc[t] = __builtin_amdgcn_mfma_f32_16x16x32_bf16(a[q], b, acc[t], 0, 0, 0);
    }
  }
  #pragma unroll
  for (int t = 0; t < 4; ++t) {
    #pragma unroll
    for (int r = 0; r < 4; ++r) {
      int rr = r0 + rgrp * 4 + r;
      if (rr < n)
        Zp[(size_t)rr * 64 + t * 16 + rl] = pack_bf16(acc[t][r], acc[t + 4][r]);
    }
  }
}

// ---------------------------------------------------------------------------
// K1: fused edge pass, 2-TILE PAIRS: 128 edges/wave-iter with 16 non-temporal
// ea loads in flight + both epilogues (ei, atomic, gathers) prefetched.
// ---------------------------------------------------------------------------
__global__ __launch_bounds__(256) void k1_edge(
    const int* __restrict__ ei, int E, const float4* __restrict__ ea4,
    const float* __restrict__ Mg,
    const float* __restrict__ a_src, const float* __restrict__ a_dst,
    uint4* __restrict__ we, int* __restrict__ deg, int* __restrict__ rank) {
  int lane = threadIdx.x & 63, wid = threadIdx.x >> 6;
  int j = lane & 7;
  const float4* Mf4 = (const float4*)Mg;
  float4 m0 = Mf4[4 * j + 0], m1 = Mf4[4 * j + 1];
  float4 m2 = Mf4[4 * j + 2], m3 = Mf4[4 * j + 3];
  int perm = 8 * (lane & 7) + (lane >> 3);
  int gw = blockIdx.x * 4 + wid, nw = gridDim.x * 4;
  int npairs = (E + 127) >> 7;
  const nf4* nea = (const nf4*)ea4;
  for (int pair = gw; pair < npairs; pair += nw) {
    int T0 = pair << 7;
    int eA = T0 + perm, eB = T0 + 64 + perm;
    bool okA = eA < E, okB = eB < E;
    // ---- index loads first ----
    int sA = 0, dA = 0, sB = 0, dB = 0;
    if (okA) { sA = ei[eA]; dA = ei[E + eA]; }
    if (okB) { sB = ei[eB]; dB = ei[E + eB]; }
    // ---- 16 stream loads in flight (non-temporal; fast path no guards) ----
    size_t fb = (size_t)T0 * 8;
    nf4 vA[8], vB[8];
    if (T0 + 128 <= E) {
      #pragma unroll
      for (int k = 0; k < 8; ++k) vA[k] = __builtin_nontemporal_load(nea + fb + (size_t)k * 64 + lane);
      #pragma unroll
      for (int k = 0; k < 8; ++k) vB[k] = __builtin_nontemporal_load(nea + fb + 512 + (size_t)k * 64 + lane);
    } else {
      #pragma unroll
      for (int k = 0; k < 8; ++k) {
        size_t idx = fb + (size_t)k * 64 + lane;
        vA[k] = (idx < (size_t)E * 8) ? __builtin_nontemporal_load(nea + idx) : (nf4){0.f, 0.f, 0.f, 0.f};
      }
      #pragma unroll
      for (int k = 0; k < 8; ++k) {
        size_t idx = fb + 512 + (size_t)k * 64 + lane;
        vB[k] = (idx < (size_t)E * 8) ? __builtin_nontemporal_load(nea + idx) : (nf4){0.f, 0.f, 0.f, 0.f};
      }
    }
    // ---- atomics + gathers (latency hides under the transposes) ----
    int rkA = 0, rkB = 0;
    float4 asA = make_float4(0.f, 0.f, 0.f, 0.f), adA = asA, asB = asA, adB = asA;
    if (okA) {
      rkA = atomicAdd(&deg[dA], 1);
      asA = *(const float4*)&a_src[(size_t)sA * 4];
      adA = *(const float4*)&a_dst[(size_t)dA * 4];
    }
    if (okB) {
      rkB = atomicAdd(&deg[dB], 1);
      asB = *(const float4*)&a_src[(size_t)sB * 4];
      adB = *(const float4*)&a_dst[(size_t)dB * 4];
    }
    // ---- transpose compute A ----
    float cxA = 0.f, cyA = 0.f, czA = 0.f, cwA = 0.f;
    #pragma unroll
    for (int k = 0; k < 8; ++k) {
      float px = vA[k].x * m0.x + vA[k].y * m1.x + vA[k].z * m2.x + vA[k].w * m3.x;
      float py = vA[k].x * m0.y + vA[k].y * m1.y + vA[k].z * m2.y + vA[k].w * m3.y;
      float pz = vA[k].x * m0.z + vA[k].y * m1.z + vA[k].z * m2.z + vA[k].w * m3.z;
      float pw = vA[k].x * m0.w + vA[k].y * m1.w + vA[k].z * m2.w + vA[k].w * m3.w;
      #pragma unroll
      for (int m = 1; m < 8; m <<= 1) {
        px += __shfl_xor(px, m); py += __shfl_xor(py, m);
        pz += __shfl_xor(pz, m); pw += __shfl_xor(pw, m);
      }
      if (j == k) { cxA = px; cyA = py; czA = pz; cwA = pw; }
    }
    // ---- transpose compute B ----
    float cxB = 0.f, cyB = 0.f, czB = 0.f, cwB = 0.f;
    #pragma unroll
    for (int k = 0; k < 8; ++k) {
      float px = vB[k].x * m0.x + vB[k].y * m1.x + vB[k].z * m2.x + vB[k].w * m3.x;
      float py = vB[k].x * m0.y + vB[k].y * m1.y + vB[k].z * m2.y + vB[k].w * m3.y;
      float pz = vB[k].x * m0.z + vB[k].y * m1.z + vB[k].z * m2.z + vB[k].w * m3.z;
      float pw = vB[k].x * m0.w + vB[k].y * m1.w + vB[k].z * m2.w + vB[k].w * m3.w;
      #pragma unroll
      for (int m = 1; m < 8; m <<= 1) {
        px += __shfl_xor(px, m); py += __shfl_xor(py, m);
        pz += __shfl_xor(pz, m); pw += __shfl_xor(pw, m);
      }
      if (j == k) { cxB = px; cyB = py; czB = pz; cwB = pw; }
    }
    // ---- epilogues ----
    if (okA) {
      float w0 = __expf(lrelu(cxA + asA.x + adA.x));
      float w1 = __expf(lrelu(cyA + asA.y + adA.y));
      float w2 = __expf(lrelu(czA + asA.z + adA.z));
      float w3 = __expf(lrelu(cwA + asA.w + adA.w));
      we[eA] = make_uint4(pack_bf16(w0, w1), pack_bf16(w2, w3),
                          pack_bf16(cxA, cyA), pack_bf16(czA, cwA));
      rank[eA] = rkA;
    }
    if (okB) {
      float w0 = __expf(lrelu(cxB + asB.x + adB.x));
      float w1 = __expf(lrelu(cyB + asB.y + adB.y));
      float w2 = __expf(lrelu(czB + asB.z + adB.z));
      float w3 = __expf(lrelu(cwB + asB.w + adB.w));
      we[eB] = make_uint4(pack_bf16(w0, w1), pack_bf16(w2, w3),
                          pack_bf16(cxB, cyB), pack_bf16(czB, cwB));
      rank[eB] = rkB;
    }
  }
}

// ---------------------------------------------------------------------------
// K2: single-block exclusive scan, all chunk loads hoisted (round-7 version).
// ---------------------------------------------------------------------------
__global__ __launch_bounds__(1024) void k2_scan(const int* __restrict__ deg, int n,
                                                int* __restrict__ offsets) {
  __shared__ int shw[16];
  __shared__ int shtot;
  int tid = threadIdx.x;
  int lane = tid & 63, wid = tid >> 6;
  int nch = (n + 4095) >> 12;
  int4 v[16];
  #pragma unroll
  for (int c = 0; c < 16; ++c) {
    if (c < nch) {
      int i = c * 4096 + tid * 4;
      int4 t = make_int4(0, 0, 0, 0);
      if (i + 3 < n) t = *(const int4*)&deg[i];
      else {
        if (i < n) t.x = deg[i];
        if (i + 1 < n) t.y = deg[i + 1];
        if (i + 2 < n) t.z = deg[i + 2];
        if (i + 3 < n) t.w = deg[i + 3];
      }
      v[c] = t;
    }
  }
  int running = 0;
  #pragma unroll
  for (int c = 0; c < 16; ++c) {
    if (c < nch) {
      int i = c * 4096 + tid * 4;
      int4 t = v[c];
      int tsum = t.x + t.y + t.z + t.w;
      int inc = tsum;
      #pragma unroll
      for (int s = 1; s < 64; s <<= 1) {
        int q = __shfl_up(inc, s);
        if (lane >= s) inc += q;
      }
      if (lane == 63) shw[wid] = inc;
      __syncthreads();
      if (wid == 0) {
        int w = (lane < 16) ? shw[lane] : 0;
        int winc = w;
        #pragma unroll
        for (int s = 1; s < 16; s <<= 1) {
          int q = __shfl_up(winc, s);
          if (lane >= s) winc += q;
        }
        if (lane < 16) shw[lane] = winc - w;
        if (lane == 15) shtot = winc;
      }
      __syncthreads();
      int excl = running + shw[wid] + inc - tsum;
      if (i < n)     offsets[i + 1] = excl + t.x;
      if (i + 1 < n) offsets[i + 2] = excl + t.x + t.y;
      if (i + 2 < n) offsets[i + 3] = excl + t.x + t.y + t.z;
      if (i + 3 < n) offsets[i + 4] = excl + tsum;
      running += shtot;
      __syncthreads();
    }
  }
  if (tid == 0) offsets[0] = 0;
}

// ---------------------------------------------------------------------------
// K4: scatter one 32B CSR entry per edge (plain stores; L2/L3 coalesce).
// ---------------------------------------------------------------------------
__global__ void k4_scatter(const int* __restrict__ ei, int E,
                           const int* __restrict__ rank, const int* __restrict__ offsets,
                           const uint4* __restrict__ we, uint4* __restrict__ csr) {
  int e = blockIdx.x * blockDim.x + threadIdx.x;
  if (e >= E) return;
  int s = ei[e], d = ei[E + e];
  int slot = offsets[d] + rank[e];
  uint4 w = we[e];
  uint4* ent = &csr[(size_t)slot * 2];
  *(int*)ent = s;
  ent[1] = w;
}

// ---------------------------------------------------------------------------
// K5: wave-per-node. Phase A: coalesced CSR stream -> dsum/aeSum partials +
// LDS stash. Phase B: Zp row gathers, UNROLL 8 for memory-level parallelism.
// ---------------------------------------------------------------------------
__global__ __launch_bounds__(256) void k5_agg(
    const int* __restrict__ offsets, const uint4* __restrict__ csr,
    const unsigned* __restrict__ Zp,
    const float* __restrict__ a_src, const float* __restrict__ a_dst,
    const float* __restrict__ cproj, int n, float* __restrict__ out) {
  __shared__ float4 s_w[4][64];
  __shared__ int    s_s[4][64];
  int tid = threadIdx.x;
  int lane = tid & 63, wid = tid >> 6;
  int gw = blockIdx.x * 4 + wid, nw = gridDim.x * 4;
  int h0 = lane >> 5, j = lane & 31;
  float cp = cproj[j];
  const float* wbase = (const float*)&s_w[wid][0];
  for (int node = gw; node < n; node += nw) {
    int off0 = offsets[node], off1 = offsets[node + 1];
    int dg = off1 - off0;
    float dsx = 0.f, dsy = 0.f, dsz = 0.f, dsw = 0.f;
    float aex = 0.f, aey = 0.f, aez = 0.f, aew = 0.f;
    float agg0 = 0.f, agg1 = 0.f;
    for (int base = off0; base < off1; base += 64) {
      int rem = off1 - base; if (rem > 64) rem = 64;
      if (lane < rem) {
        const uint4* ent = &csr[(size_t)(base + lane) * 2];
        int s = *(const int*)ent;
        uint4 w = ent[1];
        float w0 = bf16lo(w.x), w1 = bf16hi(w.x);
        float w2 = bf16lo(w.y), w3 = bf16hi(w.y);
        dsx += w0; dsy += w1; dsz += w2; dsw += w3;
        aex += bf16lo(w.z); aey += bf16hi(w.z);
        aez += bf16lo(w.w); aew += bf16hi(w.w);
        s_w[wid][lane] = make_float4(w0, w2, w1, w3);
        s_s[wid][lane] = s;
      }
      int jj = 0;
      for (; jj + 8 <= rem; jj += 8) {
        int ss[8];
        #pragma unroll
        for (int u = 0; u < 8; ++u) ss[u] = s_s[wid][jj + u];
        unsigned z[8];
        #pragma unroll
        for (int u = 0; u < 8; ++u) z[u] = Zp[(size_t)ss[u] * 64 + lane];
        #pragma unroll
        for (int u = 0; u < 8; ++u) {
          float2 w = *(const float2*)(wbase + (jj + u) * 4 + 2 * h0);
          agg0 += w.x * bf16lo(z[u]);
          agg1 += w.y * bf16hi(z[u]);
        }
      }
      for (; jj < rem; ++jj) {
        int s0 = s_s[wid][jj];
        unsigned z0 = Zp[(size_t)s0 * 64 + lane];
        float2 w0 = *(const float2*)(wbase + jj * 4 + 2 * h0);
        agg0 += w0.x * bf16lo(z0);
        agg1 += w0.y * bf16hi(z0);
      }
    }
    #pragma unroll
    for (int m = 1; m < 64; m <<= 1) {
      dsx += __shfl_xor(dsx, m); dsy += __shfl_xor(dsy, m);
      dsz += __shfl_xor(dsz, m); dsw += __shfl_xor(dsw, m);
      aex += __shfl_xor(aex, m); aey += __shfl_xor(aey, m);
      aez += __shfl_xor(aez, m); aew += __shfl_xor(aew, m);
    }
    float invd = 1.0f / (float)(dg > 0 ? dg : 1);
    float4 asn = *(const float4*)&a_src[node * 4];
    float4 ad  = *(const float4*)&a_dst[node * 4];
    float w0 = __expf(lrelu(asn.x + ad.x + aex * invd));
    float w1 = __expf(lrelu(asn.y + ad.y + aey * invd));
    float w2 = __expf(lrelu(asn.z + ad.z + aez * invd));
    float w3 = __expf(lrelu(asn.w + ad.w + aew * invd));
    dsx += w0; dsy += w1; dsz += w2; dsw += w3;
    unsigned zpn = Zp[(size_t)node * 64 + lane];
    float sw0 = h0 ? w1 : w0, sw1 = h0 ? w3 : w2;
    agg0 += sw0 * bf16lo(zpn);
    agg1 += sw1 * bf16hi(zpn);
    float d0 = h0 ? dsy : dsx, d1 = h0 ? dsw : dsz;
    float tt = agg0 / (d0 + 1e-16f) + agg1 / (d1 + 1e-16f);
    tt += __shfl_xor(tt, 32);
    if (lane < 32) out[node * 32 + j] = tt + cp;
  }
}

// ---------------------------------------------------------------------------
extern "C" void kernel_launch(void* const* d_in, const int* in_sizes, int n_in,
                              void* d_out, int out_size, void* d_ws, size_t ws_size,
                              hipStream_t stream) {
  const float* x          = (const float*)d_in[0];
  const int*   ei         = (const int*)  d_in[1];
  const float* ea         = (const float*)d_in[2];
  const float* W          = (const float*)d_in[3];
  const float* att_src    = (const float*)d_in[4];
  const float* att_dst    = (const float*)d_in[5];
  const float* lin_edge_W = (const float*)d_in[6];
  const float* att_edge   = (const float*)d_in[7];
  const float* bias       = (const float*)d_in[8];
  const float* proj_W     = (const float*)d_in[9];
  const float* proj_b     = (const float*)d_in[10];
  float* out = (float*)d_out;
  int N = in_sizes[0] / 128;
  int E = in_sizes[1] / 2;

  char* p = (char*)d_ws;
  auto alloc = [&](size_t bytes) {
    char* r = p;
    p += (bytes + 255) & ~(size_t)255;
    return r;
  };
  unsigned* Zp          = (unsigned*)alloc((size_t)N * 64 * 4);
  float* a_src          = (float*)alloc((size_t)N * 4 * 4);
  float* a_dst          = (float*)alloc((size_t)N * 4 * 4);
  int*   deg            = (int*)  alloc((size_t)N * 4);
  int*   offsets        = (int*)  alloc((size_t)(N + 1) * 4);
  int*   rank           = (int*)  alloc((size_t)E * 4);
  uint4* we             = (uint4*)alloc((size_t)E * 16);
  uint4* csr            = (uint4*)alloc((size_t)E * 32);
  unsigned short* Wzb   = (unsigned short*)alloc(16384 * 2);
  float* Ws             = (float*)alloc(128 * 4 * 4);
  float* Wd             = (float*)alloc(128 * 4 * 4);
  float* M              = (float*)alloc(32 * 4 * 4);
  float* cproj          = (float*)alloc(32 * 4);

  int b0 = ((N > 17600 ? N : 17600) + 255) / 256;
  k0_setup<<<b0, 256, 0, stream>>>(W, proj_W, att_src, att_dst, lin_edge_W, att_edge,
                                   bias, proj_b, Wzb, Ws, Wd, M, cproj, N, deg);
  k3_gemm<<<(N + 63) / 64, 256, 0, stream>>>(x, Wzb, Ws, Wd, N, Zp, a_src, a_dst);
  k1_edge<<<2048, 256, 0, stream>>>(ei, E, (const float4*)ea, M,
                                    a_src, a_dst, we, deg, rank);
  k2_scan<<<1, 1024, 0, stream>>>(deg, N, offsets);
  k4_scatter<<<(E + 255) / 256, 256, 0, stream>>>(ei, E, rank, offsets, we, csr);
  k5_agg<<<2048, 256, 0, stream>>>(offsets, csr, Zp, a_src, a_dst, cproj, N, out);
}

// Round 11
// 481.083 us; speedup vs baseline: 1.0202x; 1.0202x over previous
//
#include <hip/hip_runtime.h>

#define NEG_SLOPE 0.2f

typedef float f32x4 __attribute__((ext_vector_type(4)));
typedef short bf16x8 __attribute__((ext_vector_type(8)));
typedef float nf4 __attribute__((ext_vector_type(4)));

__device__ __forceinline__ float lrelu(float x) { return x > 0.0f ? x : NEG_SLOPE * x; }

// pack two floats as bf16 (RNE) into one uint: low16 = a, high16 = b
__device__ __forceinline__ unsigned pack_bf16(float a, float b) {
  unsigned ua = __float_as_uint(a), ub = __float_as_uint(b);
  ua += 0x7fffu + ((ua >> 16) & 1u);
  ub += 0x7fffu + ((ub >> 16) & 1u);
  return (ua >> 16) | (ub & 0xffff0000u);
}
__device__ __forceinline__ unsigned short bf16of(float a) {
  unsigned ua = __float_as_uint(a);
  ua += 0x7fffu + ((ua >> 16) & 1u);
  return (unsigned short)(ua >> 16);
}
__device__ __forceinline__ float bf16lo(unsigned z) { return __uint_as_float(z << 16); }
__device__ __forceinline__ float bf16hi(unsigned z) { return __uint_as_float(z & 0xffff0000u); }

// ---------------------------------------------------------------------------
// K0: fold all small weights + zero deg (memset folded in).
// Wzb = bf16(W @ proj_W) in MFMA-B-fragment layout.
// ---------------------------------------------------------------------------
__global__ void k0_setup(const float* __restrict__ W, const float* __restrict__ proj_W,
                         const float* __restrict__ att_src, const float* __restrict__ att_dst,
                         const float* __restrict__ lin_edge_W, const float* __restrict__ att_edge,
                         const float* __restrict__ bias, const float* __restrict__ proj_b,
                         unsigned short* __restrict__ Wzb, float* __restrict__ Ws,
                         float* __restrict__ Wd, float* __restrict__ M, float* __restrict__ cproj,
                         int n, int* __restrict__ deg) {
  int t = blockIdx.x * blockDim.x + threadIdx.x;
  if (t < n) deg[t] = 0;
  if (t < 16384) {
    int d = t >> 7, o = t & 127;
    int h = o >> 5, jj = o & 31;
    float s = 0.f;
    #pragma unroll
    for (int c = 0; c < 32; ++c)
      s += W[d * 128 + h * 32 + c] * proj_W[(h * 32 + c) * 32 + jj];
    Wzb[((d >> 3) * 128 + o) * 8 + (d & 7)] = bf16of(s);
  } else if (t < 16384 + 512) {
    int idx = t - 16384; int d = idx >> 2, h = idx & 3;
    float s = 0.f;
    #pragma unroll
    for (int c = 0; c < 32; ++c) s += W[d * 128 + h * 32 + c] * att_src[h * 32 + c];
    Ws[d * 4 + h] = s;
  } else if (t < 16384 + 1024) {
    int idx = t - 16384 - 512; int d = idx >> 2, h = idx & 3;
    float s = 0.f;
    #pragma unroll
    for (int c = 0; c < 32; ++c) s += W[d * 128 + h * 32 + c] * att_dst[h * 32 + c];
    Wd[d * 4 + h] = s;
  } else if (t < 16384 + 1024 + 128) {
    int idx = t - 16384 - 1024; int d = idx >> 2, h = idx & 3;
    float s = 0.f;
    #pragma unroll
    for (int c = 0; c < 32; ++c) s += lin_edge_W[d * 128 + h * 32 + c] * att_edge[h * 32 + c];
    M[d * 4 + h] = s;
  } else if (t < 16384 + 1024 + 128 + 32) {
    int jj = t - 16384 - 1024 - 128;
    float s = proj_b[jj];
    #pragma unroll
    for (int k = 0; k < 128; ++k) s += bias[k] * proj_W[k * 32 + jj];
    cproj[jj] = s;
  }
}

// ---------------------------------------------------------------------------
// K3: fused. Zp = bf16pack(x @ Wz) via MFMA 16x16x32 bf16, AND a_src/a_dst
// from the SAME f32 x registers. x loads are non-temporal (single-use).
// ---------------------------------------------------------------------------
__global__ __launch_bounds__(256) void k3_gemm(
    const float* __restrict__ x, const unsigned short* __restrict__ Wzb,
    const float* __restrict__ Ws, const float* __restrict__ Wd,
    int n, unsigned* __restrict__ Zp, float* __restrict__ a_src, float* __restrict__ a_dst) {
  __shared__ __align__(16) unsigned short WzL[16384];
  __shared__ float4 WsL[128];
  __shared__ float4 WdL[128];
  int tid = threadIdx.x;
  #pragma unroll
  for (int i = 0; i < 8; ++i)
    *(uint4*)&WzL[(i * 256 + tid) * 8] = *(const uint4*)&Wzb[(i * 256 + tid) * 8];
  if (tid < 128) {
    WsL[tid] = ((const float4*)Ws)[tid];
    WdL[tid] = ((const float4*)Wd)[tid];
  }
  __syncthreads();
  int lane = tid & 63, wid = tid >> 6;
  int rgrp = lane >> 4, rl = lane & 15;
  int r0 = blockIdx.x * 64 + wid * 16;
  if (r0 >= n) return;
  int row = r0 + rl;
  bool rowok = row < n;
  int rowc = rowok ? row : n - 1;
  const float* xr = x + (size_t)rowc * 128 + rgrp * 8;
  bf16x8 a[4];
  float ps[4] = {0.f, 0.f, 0.f, 0.f}, pd[4] = {0.f, 0.f, 0.f, 0.f};
  #pragma unroll
  for (int q = 0; q < 4; ++q) {
    nf4 v0 = __builtin_nontemporal_load((const nf4*)(xr + q * 32));
    nf4 v1 = __builtin_nontemporal_load((const nf4*)(xr + q * 32 + 4));
    int d0 = q * 32 + rgrp * 8;
    float vv[8] = {v0.x, v0.y, v0.z, v0.w, v1.x, v1.y, v1.z, v1.w};
    #pragma unroll
    for (int i = 0; i < 8; ++i) {
      float4 ws = WsL[d0 + i], wd = WdL[d0 + i];
      ps[0] += vv[i] * ws.x; ps[1] += vv[i] * ws.y;
      ps[2] += vv[i] * ws.z; ps[3] += vv[i] * ws.w;
      pd[0] += vv[i] * wd.x; pd[1] += vv[i] * wd.y;
      pd[2] += vv[i] * wd.z; pd[3] += vv[i] * wd.w;
    }
    union { unsigned u[4]; bf16x8 v; } fa;
    fa.u[0] = pack_bf16(v0.x, v0.y); fa.u[1] = pack_bf16(v0.z, v0.w);
    fa.u[2] = pack_bf16(v1.x, v1.y); fa.u[3] = pack_bf16(v1.z, v1.w);
    a[q] = fa.v;
  }
  #pragma unroll
  for (int m = 16; m < 64; m <<= 1) {
    #pragma unroll
    for (int h = 0; h < 4; ++h) {
      ps[h] += __shfl_xor(ps[h], m);
      pd[h] += __shfl_xor(pd[h], m);
    }
  }
  if (rgrp == 0 && rowok) {
    *(float4*)&a_src[(size_t)row * 4] = make_float4(ps[0], ps[1], ps[2], ps[3]);
    *(float4*)&a_dst[(size_t)row * 4] = make_float4(pd[0], pd[1], pd[2], pd[3]);
  }
  f32x4 acc[8];
  #pragma unroll
  for (int t = 0; t < 8; ++t) acc[t] = (f32x4){0.f, 0.f, 0.f, 0.f};
  #pragma unroll
  for (int q = 0; q < 4; ++q) {
    #pragma unroll
    for (int t = 0; t < 8; ++t) {
      bf16x8 b = *(const bf16x8*)&WzL[((q * 4 + rgrp) * 128 + t * 16 + rl) * 8];
      acc[t] = __builtin_amdgcn_mfma_f32_16x16x32_bf16(a[q], b, acc[t], 0, 0, 0);
    }
  }
  #pragma unroll
  for (int t = 0; t < 4; ++t) {
    #pragma unroll
    for (int r = 0; r < 4; ++r) {
      int rr = r0 + rgrp * 4 + r;
      if (rr < n)
        Zp[(size_t)rr * 64 + t * 16 + rl] = pack_bf16(acc[t][r], acc[t + 4][r]);
    }
  }
}

// ---------------------------------------------------------------------------
// K1: fused edge pass (round-9 exact — best measured). All 8 ea loads
// hoisted; epilogue ei loads + deg atomic + a_src/a_dst gathers issued
// before the shuffle-transpose compute.
// ---------------------------------------------------------------------------
__global__ __launch_bounds__(256) void k1_edge(
    const int* __restrict__ ei, int E, const float4* __restrict__ ea4,
    const float* __restrict__ Mg,
    const float* __restrict__ a_src, const float* __restrict__ a_dst,
    uint4* __restrict__ we, int* __restrict__ deg, int* __restrict__ rank) {
  int lane = threadIdx.x & 63, wid = threadIdx.x >> 6;
  int j = lane & 7;
  const float4* Mf4 = (const float4*)Mg;
  float4 m0 = Mf4[4 * j + 0], m1 = Mf4[4 * j + 1];
  float4 m2 = Mf4[4 * j + 2], m3 = Mf4[4 * j + 3];
  int perm = 8 * (lane & 7) + (lane >> 3);
  int gw = blockIdx.x * 4 + wid, nw = gridDim.x * 4;
  int ntiles = (E + 63) >> 6;
  for (int tile = gw; tile < ntiles; tile += nw) {
    int T0 = tile << 6;
    int e = T0 + perm;
    size_t fbase = (size_t)T0 * 8;
    int s = 0, d = 0;
    bool ok = e < E;
    if (ok) { s = ei[e]; d = ei[E + e]; }
    float4 v[8];
    if (T0 + 64 <= E) {
      #pragma unroll
      for (int k = 0; k < 8; ++k) v[k] = ea4[fbase + (size_t)k * 64 + lane];
    } else {
      #pragma unroll
      for (int k = 0; k < 8; ++k) {
        size_t idx = fbase + (size_t)k * 64 + lane;
        v[k] = (idx < (size_t)E * 8) ? ea4[idx] : make_float4(0.f, 0.f, 0.f, 0.f);
      }
    }
    int rk = 0;
    float4 as = make_float4(0.f, 0.f, 0.f, 0.f);
    float4 ad = make_float4(0.f, 0.f, 0.f, 0.f);
    if (ok) {
      rk = atomicAdd(&deg[d], 1);
      as = *(const float4*)&a_src[(size_t)s * 4];
      ad = *(const float4*)&a_dst[(size_t)d * 4];
    }
    float cx = 0.f, cy = 0.f, cz = 0.f, cw = 0.f;
    #pragma unroll
    for (int k = 0; k < 8; ++k) {
      float px = v[k].x * m0.x + v[k].y * m1.x + v[k].z * m2.x + v[k].w * m3.x;
      float py = v[k].x * m0.y + v[k].y * m1.y + v[k].z * m2.y + v[k].w * m3.y;
      float pz = v[k].x * m0.z + v[k].y * m1.z + v[k].z * m2.z + v[k].w * m3.z;
      float pw = v[k].x * m0.w + v[k].y * m1.w + v[k].z * m2.w + v[k].w * m3.w;
      #pragma unroll
      for (int m = 1; m < 8; m <<= 1) {
        px += __shfl_xor(px, m); py += __shfl_xor(py, m);
        pz += __shfl_xor(pz, m); pw += __shfl_xor(pw, m);
      }
      if (j == k) { cx = px; cy = py; cz = pz; cw = pw; }
    }
    if (ok) {
      float w0 = __expf(lrelu(cx + as.x + ad.x));
      float w1 = __expf(lrelu(cy + as.y + ad.y));
      float w2 = __expf(lrelu(cz + as.z + ad.z));
      float w3 = __expf(lrelu(cw + as.w + ad.w));
      we[e] = make_uint4(pack_bf16(w0, w1), pack_bf16(w2, w3),
                         pack_bf16(cx, cy), pack_bf16(cz, cw));
      rank[e] = rk;
    }
  }
}

// ---------------------------------------------------------------------------
// K2: single-block exclusive scan, all chunk loads hoisted.
// ---------------------------------------------------------------------------
__global__ __launch_bounds__(1024) void k2_scan(const int* __restrict__ deg, int n,
                                                int* __restrict__ offsets) {
  __shared__ int shw[16];
  __shared__ int shtot;
  int tid = threadIdx.x;
  int lane = tid & 63, wid = tid >> 6;
  int nch = (n + 4095) >> 12;
  int4 v[16];
  #pragma unroll
  for (int c = 0; c < 16; ++c) {
    if (c < nch) {
      int i = c * 4096 + tid * 4;
      int4 t = make_int4(0, 0, 0, 0);
      if (i + 3 < n) t = *(const int4*)&deg[i];
      else {
        if (i < n) t.x = deg[i];
        if (i + 1 < n) t.y = deg[i + 1];
        if (i + 2 < n) t.z = deg[i + 2];
        if (i + 3 < n) t.w = deg[i + 3];
      }
      v[c] = t;
    }
  }
  int running = 0;
  #pragma unroll
  for (int c = 0; c < 16; ++c) {
    if (c < nch) {
      int i = c * 4096 + tid * 4;
      int4 t = v[c];
      int tsum = t.x + t.y + t.z + t.w;
      int inc = tsum;
      #pragma unroll
      for (int s = 1; s < 64; s <<= 1) {
        int q = __shfl_up(inc, s);
        if (lane >= s) inc += q;
      }
      if (lane == 63) shw[wid] = inc;
      __syncthreads();
      if (wid == 0) {
        int w = (lane < 16) ? shw[lane] : 0;
        int winc = w;
        #pragma unroll
        for (int s = 1; s < 16; s <<= 1) {
          int q = __shfl_up(winc, s);
          if (lane >= s) winc += q;
        }
        if (lane < 16) shw[lane] = winc - w;
        if (lane == 15) shtot = winc;
      }
      __syncthreads();
      int excl = running + shw[wid] + inc - tsum;
      if (i < n)     offsets[i + 1] = excl + t.x;
      if (i + 1 < n) offsets[i + 2] = excl + t.x + t.y;
      if (i + 2 < n) offsets[i + 3] = excl + t.x + t.y + t.z;
      if (i + 3 < n) offsets[i + 4] = excl + tsum;
      running += shtot;
      __syncthreads();
    }
  }
  if (tid == 0) offsets[0] = 0;
}

// ---------------------------------------------------------------------------
// K4: scatter, 4 edges/thread: int4 reads of src/dst/rank (3 coalesced 16B
// loads), 4 we reads (64B contiguous), 4 offsets gathers in flight, 4
// scattered 32B entry writes. 4x per-thread MLP vs the 1-edge version.
// ---------------------------------------------------------------------------
__global__ __launch_bounds__(256) void k4_scatter(const int* __restrict__ ei, int E,
                           const int* __restrict__ rank, const int* __restrict__ offsets,
                           const uint4* __restrict__ we, uint4* __restrict__ csr) {
  int i = (blockIdx.x * blockDim.x + threadIdx.x) * 4;
  if (i + 3 < E) {
    int4 s4 = *(const int4*)&ei[i];
    int4 d4 = *(const int4*)&ei[E + i];
    int4 r4 = *(const int4*)&rank[i];
    int o0 = offsets[d4.x], o1 = offsets[d4.y], o2 = offsets[d4.z], o3 = offsets[d4.w];
    uint4 w0 = we[i], w1 = we[i + 1], w2 = we[i + 2], w3 = we[i + 3];
    uint4* e0 = &csr[(size_t)(o0 + r4.x) * 2];
    uint4* e1 = &csr[(size_t)(o1 + r4.y) * 2];
    uint4* e2 = &csr[(size_t)(o2 + r4.z) * 2];
    uint4* e3 = &csr[(size_t)(o3 + r4.w) * 2];
    *(int*)e0 = s4.x; e0[1] = w0;
    *(int*)e1 = s4.y; e1[1] = w1;
    *(int*)e2 = s4.z; e2[1] = w2;
    *(int*)e3 = s4.w; e3[1] = w3;
  } else {
    for (int e = i; e < E; ++e) {
      int s = ei[e], d = ei[E + e];
      int slot = offsets[d] + rank[e];
      uint4 w = we[e];
      uint4* ent = &csr[(size_t)slot * 2];
      *(int*)ent = s;
      ent[1] = w;
    }
  }
}

// ---------------------------------------------------------------------------
// K5: wave-per-node. Self-loop loads (a_src/a_dst/Zp[node]) hoisted ABOVE
// the edge loop so their latency overlaps phase A/B. Phase B unroll 8.
// ---------------------------------------------------------------------------
__global__ __launch_bounds__(256) void k5_agg(
    const int* __restrict__ offsets, const uint4* __restrict__ csr,
    const unsigned* __restrict__ Zp,
    const float* __restrict__ a_src, const float* __restrict__ a_dst,
    const float* __restrict__ cproj, int n, float* __restrict__ out) {
  __shared__ float4 s_w[4][64];
  __shared__ int    s_s[4][64];
  int tid = threadIdx.x;
  int lane = tid & 63, wid = tid >> 6;
  int gw = blockIdx.x * 4 + wid, nw = gridDim.x * 4;
  int h0 = lane >> 5, j = lane & 31;
  float cp = cproj[j];
  const float* wbase = (const float*)&s_w[wid][0];
  for (int node = gw; node < n; node += nw) {
    int off0 = offsets[node], off1 = offsets[node + 1];
    int dg = off1 - off0;
    // hoisted self-loop loads: latency overlaps the edge loop below
    float4 asn = *(const float4*)&a_src[(size_t)node * 4];
    float4 ad  = *(const float4*)&a_dst[(size_t)node * 4];
    unsigned zpn = Zp[(size_t)node * 64 + lane];
    float dsx = 0.f, dsy = 0.f, dsz = 0.f, dsw = 0.f;
    float aex = 0.f, aey = 0.f, aez = 0.f, aew = 0.f;
    float agg0 = 0.f, agg1 = 0.f;
    for (int base = off0; base < off1; base += 64) {
      int rem = off1 - base; if (rem > 64) rem = 64;
      if (lane < rem) {
        const uint4* ent = &csr[(size_t)(base + lane) * 2];
        int s = *(const int*)ent;
        uint4 w = ent[1];
        float w0 = bf16lo(w.x), w1 = bf16hi(w.x);
        float w2 = bf16lo(w.y), w3 = bf16hi(w.y);
        dsx += w0; dsy += w1; dsz += w2; dsw += w3;
        aex += bf16lo(w.z); aey += bf16hi(w.z);
        aez += bf16lo(w.w); aew += bf16hi(w.w);
        s_w[wid][lane] = make_float4(w0, w2, w1, w3);
        s_s[wid][lane] = s;
      }
      int jj = 0;
      for (; jj + 8 <= rem; jj += 8) {
        int ss[8];
        #pragma unroll
        for (int u = 0; u < 8; ++u) ss[u] = s_s[wid][jj + u];
        unsigned z[8];
        #pragma unroll
        for (int u = 0; u < 8; ++u) z[u] = Zp[(size_t)ss[u] * 64 + lane];
        #pragma unroll
        for (int u = 0; u < 8; ++u) {
          float2 w = *(const float2*)(wbase + (jj + u) * 4 + 2 * h0);
          agg0 += w.x * bf16lo(z[u]);
          agg1 += w.y * bf16hi(z[u]);
        }
      }
      for (; jj < rem; ++jj) {
        int s0 = s_s[wid][jj];
        unsigned z0 = Zp[(size_t)s0 * 64 + lane];
        float2 w0 = *(const float2*)(wbase + jj * 4 + 2 * h0);
        agg0 += w0.x * bf16lo(z0);
        agg1 += w0.y * bf16hi(z0);
      }
    }
    #pragma unroll
    for (int m = 1; m < 64; m <<= 1) {
      dsx += __shfl_xor(dsx, m); dsy += __shfl_xor(dsy, m);
      dsz += __shfl_xor(dsz, m); dsw += __shfl_xor(dsw, m);
      aex += __shfl_xor(aex, m); aey += __shfl_xor(aey, m);
      aez += __shfl_xor(aez, m); aew += __shfl_xor(aew, m);
    }
    float invd = 1.0f / (float)(dg > 0 ? dg : 1);
    float w0 = __expf(lrelu(asn.x + ad.x + aex * invd));
    float w1 = __expf(lrelu(asn.y + ad.y + aey * invd));
    float w2 = __expf(lrelu(asn.z + ad.z + aez * invd));
    float w3 = __expf(lrelu(asn.w + ad.w + aew * invd));
    dsx += w0; dsy += w1; dsz += w2; dsw += w3;
    float sw0 = h0 ? w1 : w0, sw1 = h0 ? w3 : w2;
    agg0 += sw0 * bf16lo(zpn);
    agg1 += sw1 * bf16hi(zpn);
    float d0 = h0 ? dsy : dsx, d1 = h0 ? dsw : dsz;
    float tt = agg0 / (d0 + 1e-16f) + agg1 / (d1 + 1e-16f);
    tt += __shfl_xor(tt, 32);
    if (lane < 32) out[node * 32 + j] = tt + cp;
  }
}

// ---------------------------------------------------------------------------
extern "C" void kernel_launch(void* const* d_in, const int* in_sizes, int n_in,
                              void* d_out, int out_size, void* d_ws, size_t ws_size,
                              hipStream_t stream) {
  const float* x          = (const float*)d_in[0];
  const int*   ei         = (const int*)  d_in[1];
  const float* ea         = (const float*)d_in[2];
  const float* W          = (const float*)d_in[3];
  const float* att_src    = (const float*)d_in[4];
  const float* att_dst    = (const float*)d_in[5];
  const float* lin_edge_W = (const float*)d_in[6];
  const float* att_edge   = (const float*)d_in[7];
  const float* bias       = (const float*)d_in[8];
  const float* proj_W     = (const float*)d_in[9];
  const float* proj_b     = (const float*)d_in[10];
  float* out = (float*)d_out;
  int N = in_sizes[0] / 128;
  int E = in_sizes[1] / 2;

  char* p = (char*)d_ws;
  auto alloc = [&](size_t bytes) {
    char* r = p;
    p += (bytes + 255) & ~(size_t)255;
    return r;
  };
  unsigned* Zp          = (unsigned*)alloc((size_t)N * 64 * 4);
  float* a_src          = (float*)alloc((size_t)N * 4 * 4);
  float* a_dst          = (float*)alloc((size_t)N * 4 * 4);
  int*   deg            = (int*)  alloc((size_t)N * 4);
  int*   offsets        = (int*)  alloc((size_t)(N + 1) * 4);
  int*   rank           = (int*)  alloc((size_t)E * 4);
  uint4* we             = (uint4*)alloc((size_t)E * 16);
  uint4* csr            = (uint4*)alloc((size_t)E * 32);
  unsigned short* Wzb   = (unsigned short*)alloc(16384 * 2);
  float* Ws             = (float*)alloc(128 * 4 * 4);
  float* Wd             = (float*)alloc(128 * 4 * 4);
  float* M              = (float*)alloc(32 * 4 * 4);
  float* cproj          = (float*)alloc(32 * 4);

  int b0 = ((N > 17600 ? N : 17600) + 255) / 256;
  k0_setup<<<b0, 256, 0, stream>>>(W, proj_W, att_src, att_dst, lin_edge_W, att_edge,
                                   bias, proj_b, Wzb, Ws, Wd, M, cproj, N, deg);
  k3_gemm<<<(N + 63) / 64, 256, 0, stream>>>(x, Wzb, Ws, Wd, N, Zp, a_src, a_dst);
  k1_edge<<<2048, 256, 0, stream>>>(ei, E, (const float4*)ea, M,
                                    a_src, a_dst, we, deg, rank);
  k2_scan<<<1, 1024, 0, stream>>>(deg, N, offsets);
  k4_scatter<<<(E / 4 + 256) / 256, 256, 0, stream>>>(ei, E, rank, offsets, we, csr);
  k5_agg<<<2048, 256, 0, stream>>>(offsets, csr, Zp, a_src, a_dst, cproj, N, out);
}